// Round 5
// baseline (266.949 us; speedup 1.0000x reference)
//
#include <hip/hip_runtime.h>

// Problem constants (from reference setup_inputs)
constexpr int N = 16, H = 768, W = 768;
constexpr int HW = H * W;
constexpr float EPS2 = 1.0e-6f;           // EPS^2, EPS = 0.001
constexpr float INV_W1 = 1.0f / (float)(W - 1);
constexpr float INV_H1 = 1.0f / (float)(H - 1);
constexpr float WM1 = (float)(W - 1);
constexpr float HM1 = (float)(H - 1);
constexpr float WM2 = (float)(W - 2);

// LDS tile: output 64 cols x 16 rows per block; halo 8 cols / 4 rows.
constexpr int TILE_COLS = 80;             // staged cols: [bx0-8, bx0+72)
constexpr int TILE_ROWS = 24;             // staged rows: [by0-4, by0+20)
constexpr int C_HALO = 8;
constexpr int R_HALO = 4;
constexpr int LSTRIDE = TILE_COLS;        // 80 floats/row
constexpr int PLANE = TILE_ROWS * LSTRIDE; // 1920 floats per plane
// planes: 0=A.x 1=A.y 2=B.x 3=B.y  → 4*1920*4B = 30720 B LDS

// 8-byte vector with 4-byte alignment promise
typedef float float2a __attribute__((ext_vector_type(2), aligned(4)));

struct DirMeta { float gx, gy; int xb, y0, y1; };  // clamped pair base / rows

__device__ __forceinline__ void dir_meta(float fx, float fy, int x, int y, DirMeta& m) {
    m.gx = (float)x + fx;
    m.gy = (float)y + fy;
    float x0f = floorf(m.gx);
    float y0f = floorf(m.gy);
    m.xb = (int)fminf(fmaxf(x0f, 0.0f), WM2);          // pair cols {xb, xb+1}
    m.y0 = (int)fminf(fmaxf(y0f, 0.0f), HM1);
    m.y1 = (int)fminf(fmaxf(y0f + 1.0f, 0.0f), HM1);
}

// ---------- fast path (verified round 4) ----------------------------------
__device__ __forceinline__ bool fast_ok(const DirMeta& m,
                                        float2a g0, float2a g1, float2a g2, float2a g3) {
    float x0f = floorf(m.gx), y0f = floorf(m.gy);
    bool ok = (x0f >= 0.0f) & (x0f <= WM2) & (y0f >= 0.0f) & (y0f <= HM1 - 1.0f);
    float x1f = x0f + 1.0f, y1f = y0f + 1.0f;
    float gx00 = x0f + g0.x, gx01 = x1f + g0.y;
    float gx10 = x0f + g2.x, gx11 = x1f + g2.y;
    float gy00 = y0f + g1.x, gy01 = y0f + g1.y;
    float gy10 = y1f + g3.x, gy11 = y1f + g3.y;
    float xlo = fminf(fminf(gx00, gx01), fminf(gx10, gx11));
    float xhi = fmaxf(fmaxf(gx00, gx01), fmaxf(gx10, gx11));
    float ylo = fminf(fminf(gy00, gy01), fminf(gy10, gy11));
    float yhi = fmaxf(fmaxf(gy00, gy01), fmaxf(gy10, gy11));
    ok &= (xlo >= 0.0f) & (xhi <= WM1) & (ylo >= 0.0f) & (yhi <= HM1);
    return ok;
}

__device__ __forceinline__ float fast_eval(const DirMeta& m,
                                           float2a g0, float2a g1, float2a g2, float2a g3,
                                           float fxc, float fyc) {
    float x0f = floorf(m.gx), y0f = floorf(m.gy);
    float wx1 = m.gx - x0f, wy1 = m.gy - y0f;
    float ftx = fmaf(wx1, g0.y - g0.x, g0.x);
    float fbx = fmaf(wx1, g2.y - g2.x, g2.x);
    float fxv = fmaf(wy1, fbx - ftx, ftx);
    float fty = fmaf(wx1, g1.y - g1.x, g1.x);
    float fby = fmaf(wx1, g3.y - g3.x, g3.x);
    float fyv = fmaf(wy1, fby - fty, fty);
    float a = (fxc + fxv) * INV_W1;
    float b = (fyc + fyv) * INV_H1;
    return sqrtf(fmaf(a, a, fmaf(b, b, EPS2)));
}

// ---------- general (border / wild-flow) path (verified round 4) ----------
__device__ __forceinline__ float2 wg(float fx, float fy, float xi, float yi) {
    float gx = xi + fx, gy = yi + fy;
    float x0 = floorf(gx), y0 = floorf(gy);
    float wx1 = gx - x0, wx0 = 1.0f - wx1;
    float wy1 = gy - y0, wy0 = 1.0f - wy1;
    float vx0 = (x0 >= 0.0f  && x0 <= WM1)        ? 1.0f : 0.0f;
    float vx1 = (x0 >= -1.0f && x0 <= WM1 - 1.0f) ? 1.0f : 0.0f;
    float vy0 = (y0 >= 0.0f  && y0 <= HM1)        ? 1.0f : 0.0f;
    float vy1 = (y0 >= -1.0f && y0 <= HM1 - 1.0f) ? 1.0f : 0.0f;
    float ax = wx0 * vx0, bx = wx1 * vx1, sx = ax + bx;
    float ay = wy0 * vy0, by = wy1 * vy1, sy = ay + by;
    float ms = sx * sy;
    float kx = (ms >= 0.9999f) ? INV_W1 : 0.0f;
    float ky = (ms >= 0.9999f) ? INV_H1 : 0.0f;
    float2 r;
    r.x = fmaf(sx, x0, bx) * sy * kx;
    r.y = fmaf(sy, y0, by) * sx * ky;
    return r;
}

__device__ __forceinline__ float dir_eval(const DirMeta& m,
                                          float2a r0x, float2a r0y,
                                          float2a r1x, float2a r1y,
                                          int x, int y) {
    float x0f = floorf(m.gx), y0f = floorf(m.gy);
    float wx1 = m.gx - x0f, wx0 = 1.0f - wx1;
    float wy1 = m.gy - y0f, wy0 = 1.0f - wy1;
    float x1f = x0f + 1.0f, y1f = y0f + 1.0f;
    float vx0 = (x0f >= 0.0f && x0f <= WM1) ? 1.0f : 0.0f;
    float vx1 = (x1f >= 0.0f && x1f <= WM1) ? 1.0f : 0.0f;
    float vy0 = (y0f >= 0.0f && y0f <= HM1) ? 1.0f : 0.0f;
    float vy1 = (y1f >= 0.0f && y1f <= HM1) ? 1.0f : 0.0f;
    float axw = wx0 * vx0, bxw = wx1 * vx1;
    float ayw = wy0 * vy0, byw = wy1 * vy1;
    float sxw = axw + bxw, syw = ayw + byw;
    float msum = sxw * syw;

    bool selA = (x0f >= WM1);     // pair base xb = clamp(x0,0,W-2)
    bool selB = (x0f >= 0.0f);
    float fx00 = selA ? r0x.y : r0x.x;
    float fx01 = selB ? r0x.y : r0x.x;
    float fy00 = selA ? r0y.y : r0y.x;
    float fy01 = selB ? r0y.y : r0y.x;
    float fx10 = selA ? r1x.y : r1x.x;
    float fx11 = selB ? r1x.y : r1x.x;
    float fy10 = selA ? r1y.y : r1y.x;
    float fy11 = selB ? r1y.y : r1y.x;

    float x0c = fminf(fmaxf(x0f, 0.0f), WM1);
    float x1c = fminf(fmaxf(x1f, 0.0f), WM1);
    float y0c = fminf(fmaxf(y0f, 0.0f), HM1);
    float y1c = fminf(fmaxf(y1f, 0.0f), HM1);

    float2 m00 = wg(fx00, fy00, x0c, y0c);
    float2 m01 = wg(fx01, fy01, x1c, y0c);
    float2 m10 = wg(fx10, fy10, x0c, y1c);
    float2 m11 = wg(fx11, fy11, x1c, y1c);

    float w00 = axw * ayw, w10 = bxw * ayw, w01 = axw * byw, w11 = bxw * byw;
    float mx = w00 * m00.x + w10 * m01.x + w01 * m10.x + w11 * m11.x;
    float my = w00 * m00.y + w10 * m01.y + w01 * m10.y + w11 * m11.y;
    float keep = (msum >= 0.9999f) ? 1.0f : 0.0f;
    mx *= keep; my *= keep;

    float dx = (float)x * INV_W1 - mx;
    float dy = (float)y * INV_H1 - my;
    return sqrtf(fmaf(dx, dx, fmaf(dy, dy, EPS2)));
}

__global__ __launch_bounds__(256, 5)
void cycle_loss_kernel(const float* __restrict__ A,   // UV_AtoB
                       const float* __restrict__ B,   // UV_BtoA
                       float* __restrict__ out) {
    __shared__ float lds[4 * PLANE];
    __shared__ float wsum[4];

    int tid  = threadIdx.x;
    int lane = tid & 63;
    int wv   = tid >> 6;
    int bx0 = blockIdx.x * 64;
    int by0 = blockIdx.y * 16;
    int b   = blockIdx.z;
    const float* Ab = A + (size_t)b * 2 * HW;
    const float* Bb = B + (size_t)b * 2 * HW;
    int tc0 = bx0 - C_HALO;    // may be negative at borders
    int tr0 = by0 - R_HALO;

    // ---- stage 4 planes via coalesced float4 loads -> ds_write_b128 ----
    // chunks: 4 planes * 24 rows * 20 float4-chunks = 1920 tasks.
    // Chunks are 4-col aligned and W%4==0, so a chunk is entirely in- or
    // out-of-image; out-of-image cells stay unwritten and are provably
    // never read (eligible reads use image-clamped coords).
    for (int i = tid; i < 4 * TILE_ROWS * (TILE_COLS / 4); i += 256) {
        int plane = i / (TILE_ROWS * (TILE_COLS / 4));
        int rem   = i - plane * (TILE_ROWS * (TILE_COLS / 4));
        int lr    = rem / (TILE_COLS / 4);
        int lc    = rem - lr * (TILE_COLS / 4);
        int rg = tr0 + lr;
        int cg = tc0 + lc * 4;
        if ((unsigned)rg < (unsigned)H && (unsigned)cg < (unsigned)W) {
            const float* src = (plane < 2 ? Ab : Bb) + (plane & 1) * HW;
            float4 v = *(const float4*)(src + rg * W + cg);
            *(float4*)&lds[plane * PLANE + lr * LSTRIDE + lc * 4] = v;
        }
    }
    __syncthreads();

    int x  = bx0 + lane;
    int yb = by0 + wv * 4;        // 4 consecutive rows per thread
    int lxc = lane + C_HALO;      // x - tc0

    // centers from LDS (stride-1: conflict-free)
    float aX[4], aY[4], bX[4], bY[4];
    #pragma unroll
    for (int p = 0; p < 4; ++p) {
        int o = (wv * 4 + p + R_HALO) * LSTRIDE + lxc;
        aX[p] = lds[0 * PLANE + o];
        aY[p] = lds[1 * PLANE + o];
        bX[p] = lds[2 * PLANE + o];
        bY[p] = lds[3 * PLANE + o];
    }

    float s = 0.0f;
    #pragma unroll
    for (int p = 0; p < 4; ++p) {
        int y = yb + p;
        DirMeta m1, m2;
        dir_meta(bX[p], bY[p], x, y, m1);   // ABA: outer flow B, gather A
        dir_meta(aX[p], aY[p], x, y, m2);   // BAB: outer flow A, gather B

        bool e1 = (m1.xb >= tc0) & (m1.xb <= tc0 + TILE_COLS - 2)
                & (m1.y0 >= tr0) & (m1.y1 <= tr0 + TILE_ROWS - 1);
        bool e2 = (m2.xb >= tc0) & (m2.xb <= tc0 + TILE_COLS - 2)
                & (m2.y0 >= tr0) & (m2.y1 <= tr0 + TILE_ROWS - 1);

        float2a g1[4], g2[4];
        if (__all(e1 & e2)) {
            int i10 = (m1.y0 - tr0) * LSTRIDE + (m1.xb - tc0);
            int i11 = (m1.y1 - tr0) * LSTRIDE + (m1.xb - tc0);
            g1[0].x = lds[0 * PLANE + i10]; g1[0].y = lds[0 * PLANE + i10 + 1];
            g1[1].x = lds[1 * PLANE + i10]; g1[1].y = lds[1 * PLANE + i10 + 1];
            g1[2].x = lds[0 * PLANE + i11]; g1[2].y = lds[0 * PLANE + i11 + 1];
            g1[3].x = lds[1 * PLANE + i11]; g1[3].y = lds[1 * PLANE + i11 + 1];
            int i20 = (m2.y0 - tr0) * LSTRIDE + (m2.xb - tc0);
            int i21 = (m2.y1 - tr0) * LSTRIDE + (m2.xb - tc0);
            g2[0].x = lds[2 * PLANE + i20]; g2[0].y = lds[2 * PLANE + i20 + 1];
            g2[1].x = lds[3 * PLANE + i20]; g2[1].y = lds[3 * PLANE + i20 + 1];
            g2[2].x = lds[2 * PLANE + i21]; g2[2].y = lds[2 * PLANE + i21 + 1];
            g2[3].x = lds[3 * PLANE + i21]; g2[3].y = lds[3 * PLANE + i21 + 1];
        } else {
            // rare (P ~1e-4/pixel-dir): per-lane LDS/global select
            if (e1) {
                int i10 = (m1.y0 - tr0) * LSTRIDE + (m1.xb - tc0);
                int i11 = (m1.y1 - tr0) * LSTRIDE + (m1.xb - tc0);
                g1[0].x = lds[0 * PLANE + i10]; g1[0].y = lds[0 * PLANE + i10 + 1];
                g1[1].x = lds[1 * PLANE + i10]; g1[1].y = lds[1 * PLANE + i10 + 1];
                g1[2].x = lds[0 * PLANE + i11]; g1[2].y = lds[0 * PLANE + i11 + 1];
                g1[3].x = lds[1 * PLANE + i11]; g1[3].y = lds[1 * PLANE + i11 + 1];
            } else {
                int o0 = m1.y0 * W + m1.xb, o1 = m1.y1 * W + m1.xb;
                g1[0] = *(const float2a*)(Ab + o0);
                g1[1] = *(const float2a*)(Ab + HW + o0);
                g1[2] = *(const float2a*)(Ab + o1);
                g1[3] = *(const float2a*)(Ab + HW + o1);
            }
            if (e2) {
                int i20 = (m2.y0 - tr0) * LSTRIDE + (m2.xb - tc0);
                int i21 = (m2.y1 - tr0) * LSTRIDE + (m2.xb - tc0);
                g2[0].x = lds[2 * PLANE + i20]; g2[0].y = lds[2 * PLANE + i20 + 1];
                g2[1].x = lds[3 * PLANE + i20]; g2[1].y = lds[3 * PLANE + i20 + 1];
                g2[2].x = lds[2 * PLANE + i21]; g2[2].y = lds[2 * PLANE + i21 + 1];
                g2[3].x = lds[3 * PLANE + i21]; g2[3].y = lds[3 * PLANE + i21 + 1];
            } else {
                int o0 = m2.y0 * W + m2.xb, o1 = m2.y1 * W + m2.xb;
                g2[0] = *(const float2a*)(Bb + o0);
                g2[1] = *(const float2a*)(Bb + HW + o0);
                g2[2] = *(const float2a*)(Bb + o1);
                g2[3] = *(const float2a*)(Bb + HW + o1);
            }
        }

        bool ok = fast_ok(m1, g1[0], g1[1], g1[2], g1[3])
                & fast_ok(m2, g2[0], g2[1], g2[2], g2[3]);
        if (__all(ok)) {
            s += fast_eval(m1, g1[0], g1[1], g1[2], g1[3], bX[p], bY[p]);
            s += fast_eval(m2, g2[0], g2[1], g2[2], g2[3], aX[p], aY[p]);
        } else {
            s += dir_eval(m1, g1[0], g1[1], g1[2], g1[3], x, y);
            s += dir_eval(m2, g2[0], g2[1], g2[2], g2[3], x, y);
        }
    }

    // wave(64) shuffle reduce -> LDS -> one atomic per block
    #pragma unroll
    for (int o = 32; o > 0; o >>= 1) s += __shfl_down(s, o, 64);
    if (lane == 0) wsum[wv] = s;
    __syncthreads();
    if (tid == 0) {
        float tsum = wsum[0] + wsum[1] + wsum[2] + wsum[3];
        atomicAdd(out, tsum * (1.0f / ((float)N * (float)H * (float)W)));
    }
}

extern "C" void kernel_launch(void* const* d_in, const int* in_sizes, int n_in,
                              void* d_out, int out_size, void* d_ws, size_t ws_size,
                              hipStream_t stream) {
    const float* A = (const float*)d_in[0];   // UV_AtoB [16,2,768,768]
    const float* B = (const float*)d_in[1];   // UV_BtoA [16,2,768,768]
    float* out = (float*)d_out;               // scalar fp32

    hipMemsetAsync(out, 0, sizeof(float), stream);

    dim3 grid(W / 64, H / 16, N);             // (12, 48, 16) = 9216 blocks
    cycle_loss_kernel<<<grid, 256, 0, stream>>>(A, B, out);
}

// Round 6
// 209.919 us; speedup vs baseline: 1.2717x; 1.2717x over previous
//
#include <hip/hip_runtime.h>

// Problem constants (from reference setup_inputs)
constexpr int N = 16, H = 768, W = 768;
constexpr int HW = H * W;
constexpr float EPS2 = 1.0e-6f;           // EPS^2, EPS = 0.001
constexpr float INV_W1 = 1.0f / (float)(W - 1);
constexpr float INV_H1 = 1.0f / (float)(H - 1);
constexpr float WM1 = (float)(W - 1);
constexpr float HM1 = (float)(H - 1);
constexpr float WM2 = (float)(W - 2);

// LDS tile: output 64 cols x 16 rows per block; halo 8 cols / 4 rows.
// Layout: interleaved {fx,fy} float2 per pixel -> pair gather = ds_read2_b64.
constexpr int TILE_COLS = 80;              // staged cols: [bx0-8, bx0+72)
constexpr int TILE_ROWS = 24;              // staged rows: [by0-4, by0+20)
constexpr int C_HALO = 8;
constexpr int R_HALO = 4;
constexpr int LSTRIDE = TILE_COLS;         // pixels per tile row
constexpr int TILE_FLOATS = TILE_ROWS * LSTRIDE * 2;  // 3840 floats per tensor
constexpr int NBLK_X = W / 64, NBLK_Y = H / 16;       // 12, 48
constexpr int NBLOCKS = NBLK_X * NBLK_Y * N;          // 9216

// 8-byte vector with 4-byte alignment promise
typedef float float2a __attribute__((ext_vector_type(2), aligned(4)));

struct DirMeta { float gx, gy; int xb, y0, y1; };  // clamped pair base / rows

__device__ __forceinline__ void dir_meta(float fx, float fy, int x, int y, DirMeta& m) {
    m.gx = (float)x + fx;
    m.gy = (float)y + fy;
    float x0f = floorf(m.gx);
    float y0f = floorf(m.gy);
    m.xb = (int)fminf(fmaxf(x0f, 0.0f), WM2);          // pair cols {xb, xb+1}
    m.y0 = (int)fminf(fmaxf(y0f, 0.0f), HM1);
    m.y1 = (int)fminf(fmaxf(y0f + 1.0f, 0.0f), HM1);
}

// ---------- fast path (verified rounds 4-5) --------------------------------
__device__ __forceinline__ bool fast_ok(const DirMeta& m,
                                        float2a g0, float2a g1, float2a g2, float2a g3) {
    float x0f = floorf(m.gx), y0f = floorf(m.gy);
    bool ok = (x0f >= 0.0f) & (x0f <= WM2) & (y0f >= 0.0f) & (y0f <= HM1 - 1.0f);
    float x1f = x0f + 1.0f, y1f = y0f + 1.0f;
    float gx00 = x0f + g0.x, gx01 = x1f + g0.y;
    float gx10 = x0f + g2.x, gx11 = x1f + g2.y;
    float gy00 = y0f + g1.x, gy01 = y0f + g1.y;
    float gy10 = y1f + g3.x, gy11 = y1f + g3.y;
    float xlo = fminf(fminf(gx00, gx01), fminf(gx10, gx11));
    float xhi = fmaxf(fmaxf(gx00, gx01), fmaxf(gx10, gx11));
    float ylo = fminf(fminf(gy00, gy01), fminf(gy10, gy11));
    float yhi = fmaxf(fmaxf(gy00, gy01), fmaxf(gy10, gy11));
    ok &= (xlo >= 0.0f) & (xhi <= WM1) & (ylo >= 0.0f) & (yhi <= HM1);
    return ok;
}

__device__ __forceinline__ float fast_eval(const DirMeta& m,
                                           float2a g0, float2a g1, float2a g2, float2a g3,
                                           float fxc, float fyc) {
    float x0f = floorf(m.gx), y0f = floorf(m.gy);
    float wx1 = m.gx - x0f, wy1 = m.gy - y0f;
    float ftx = fmaf(wx1, g0.y - g0.x, g0.x);
    float fbx = fmaf(wx1, g2.y - g2.x, g2.x);
    float fxv = fmaf(wy1, fbx - ftx, ftx);
    float fty = fmaf(wx1, g1.y - g1.x, g1.x);
    float fby = fmaf(wx1, g3.y - g3.x, g3.x);
    float fyv = fmaf(wy1, fby - fty, fty);
    float a = (fxc + fxv) * INV_W1;
    float b = (fyc + fyv) * INV_H1;
    return sqrtf(fmaf(a, a, fmaf(b, b, EPS2)));
}

// ---------- general (border / wild-flow) path (verified rounds 4-5) --------
__device__ __forceinline__ float2 wg(float fx, float fy, float xi, float yi) {
    float gx = xi + fx, gy = yi + fy;
    float x0 = floorf(gx), y0 = floorf(gy);
    float wx1 = gx - x0, wx0 = 1.0f - wx1;
    float wy1 = gy - y0, wy0 = 1.0f - wy1;
    float vx0 = (x0 >= 0.0f  && x0 <= WM1)        ? 1.0f : 0.0f;
    float vx1 = (x0 >= -1.0f && x0 <= WM1 - 1.0f) ? 1.0f : 0.0f;
    float vy0 = (y0 >= 0.0f  && y0 <= HM1)        ? 1.0f : 0.0f;
    float vy1 = (y0 >= -1.0f && y0 <= HM1 - 1.0f) ? 1.0f : 0.0f;
    float ax = wx0 * vx0, bx = wx1 * vx1, sx = ax + bx;
    float ay = wy0 * vy0, by = wy1 * vy1, sy = ay + by;
    float ms = sx * sy;
    float kx = (ms >= 0.9999f) ? INV_W1 : 0.0f;
    float ky = (ms >= 0.9999f) ? INV_H1 : 0.0f;
    float2 r;
    r.x = fmaf(sx, x0, bx) * sy * kx;
    r.y = fmaf(sy, y0, by) * sx * ky;
    return r;
}

__device__ __forceinline__ float dir_eval(const DirMeta& m,
                                          float2a r0x, float2a r0y,
                                          float2a r1x, float2a r1y,
                                          int x, int y) {
    float x0f = floorf(m.gx), y0f = floorf(m.gy);
    float wx1 = m.gx - x0f, wx0 = 1.0f - wx1;
    float wy1 = m.gy - y0f, wy0 = 1.0f - wy1;
    float x1f = x0f + 1.0f, y1f = y0f + 1.0f;
    float vx0 = (x0f >= 0.0f && x0f <= WM1) ? 1.0f : 0.0f;
    float vx1 = (x1f >= 0.0f && x1f <= WM1) ? 1.0f : 0.0f;
    float vy0 = (y0f >= 0.0f && y0f <= HM1) ? 1.0f : 0.0f;
    float vy1 = (y1f >= 0.0f && y1f <= HM1) ? 1.0f : 0.0f;
    float axw = wx0 * vx0, bxw = wx1 * vx1;
    float ayw = wy0 * vy0, byw = wy1 * vy1;
    float sxw = axw + bxw, syw = ayw + byw;
    float msum = sxw * syw;

    bool selA = (x0f >= WM1);     // pair base xb = clamp(x0,0,W-2)
    bool selB = (x0f >= 0.0f);
    float fx00 = selA ? r0x.y : r0x.x;
    float fx01 = selB ? r0x.y : r0x.x;
    float fy00 = selA ? r0y.y : r0y.x;
    float fy01 = selB ? r0y.y : r0y.x;
    float fx10 = selA ? r1x.y : r1x.x;
    float fx11 = selB ? r1x.y : r1x.x;
    float fy10 = selA ? r1y.y : r1y.x;
    float fy11 = selB ? r1y.y : r1y.x;

    float x0c = fminf(fmaxf(x0f, 0.0f), WM1);
    float x1c = fminf(fmaxf(x1f, 0.0f), WM1);
    float y0c = fminf(fmaxf(y0f, 0.0f), HM1);
    float y1c = fminf(fmaxf(y1f, 0.0f), HM1);

    float2 m00 = wg(fx00, fy00, x0c, y0c);
    float2 m01 = wg(fx01, fy01, x1c, y0c);
    float2 m10 = wg(fx10, fy10, x0c, y1c);
    float2 m11 = wg(fx11, fy11, x1c, y1c);

    float w00 = axw * ayw, w10 = bxw * ayw, w01 = axw * byw, w11 = bxw * byw;
    float mx = w00 * m00.x + w10 * m01.x + w01 * m10.x + w11 * m11.x;
    float my = w00 * m00.y + w10 * m01.y + w01 * m10.y + w11 * m11.y;
    float keep = (msum >= 0.9999f) ? 1.0f : 0.0f;
    mx *= keep; my *= keep;

    float dx = (float)x * INV_W1 - mx;
    float dy = (float)y * INV_H1 - my;
    return sqrtf(fmaf(dx, dx, fmaf(dy, dy, EPS2)));
}

// Load the 4 floats {fx0,fy0,fx1,fy1} of pixel pair (pix, pix+1) from an
// interleaved tile. Two adjacent 8B loads, one base -> fuses to ds_read2_b64.
__device__ __forceinline__ void ld_quad(const float* t, int pix,
                                        float2a& gx, float2a& gy) {
    float2 u = *(const float2*)(t + 2 * pix);
    float2 v = *(const float2*)(t + 2 * pix + 2);
    gx.x = u.x; gx.y = v.x;
    gy.x = u.y; gy.y = v.y;
}

__global__ __launch_bounds__(256)
void cycle_loss_kernel(const float* __restrict__ A,   // UV_AtoB
                       const float* __restrict__ B,   // UV_BtoA
                       float* __restrict__ ws,
                       float* __restrict__ out,
                       int use_ws) {
    __shared__ float lds[2 * TILE_FLOATS];   // [0]=A tile, [3840]=B tile
    __shared__ float wsum[4];

    int tid  = threadIdx.x;
    int lane = tid & 63;
    int wv   = tid >> 6;
    int bx0 = blockIdx.x * 64;
    int by0 = blockIdx.y * 16;
    int b   = blockIdx.z;
    const float* Ab = A + (size_t)b * 2 * HW;
    const float* Bb = B + (size_t)b * 2 * HW;
    int tc0 = bx0 - C_HALO;
    int tr0 = by0 - R_HALO;

    // ---- stage both tensors as interleaved {fx,fy} tiles -----------------
    // 960 tasks: tensor(2) x row(24) x float4-col-chunk(20). Each task: two
    // coalesced global float4 loads (fx,fy planes) -> two 16B LDS writes.
    // Chunks are 4-col aligned & W%4==0 -> whole chunk in- or out-of-image;
    // out-of-image cells stay unwritten and are provably never read.
    for (int i = tid; i < 2 * TILE_ROWS * (TILE_COLS / 4); i += 256) {
        int t   = i / (TILE_ROWS * (TILE_COLS / 4));
        int rem = i - t * (TILE_ROWS * (TILE_COLS / 4));
        int lr  = rem / (TILE_COLS / 4);
        int lc4 = rem - lr * (TILE_COLS / 4);
        int rg = tr0 + lr;
        int cg = tc0 + lc4 * 4;
        if ((unsigned)rg < (unsigned)H && (unsigned)cg < (unsigned)W) {
            const float* src = (t ? Bb : Ab) + rg * W + cg;
            float4 fx = *(const float4*)(src);
            float4 fy = *(const float4*)(src + HW);
            float* dst = &lds[t * TILE_FLOATS + (lr * LSTRIDE + lc4 * 4) * 2];
            *(float4*)(dst)     = make_float4(fx.x, fy.x, fx.y, fy.y);
            *(float4*)(dst + 4) = make_float4(fx.z, fy.z, fx.w, fy.w);
        }
    }
    __syncthreads();

    const float* ldsA = lds;
    const float* ldsB = lds + TILE_FLOATS;
    int x  = bx0 + lane;
    int yb = by0 + wv * 4;        // 4 consecutive rows per thread
    int lxc = lane + C_HALO;

    // centers: one conflict-free ds_read_b64 per tensor per pixel
    float2 aC[4], bC[4];
    #pragma unroll
    for (int p = 0; p < 4; ++p) {
        int co = (wv * 4 + p + R_HALO) * LSTRIDE + lxc;
        aC[p] = *(const float2*)(ldsA + 2 * co);
        bC[p] = *(const float2*)(ldsB + 2 * co);
    }

    float s = 0.0f;
    #pragma unroll
    for (int p = 0; p < 4; ++p) {
        int y = yb + p;
        DirMeta m1, m2;
        dir_meta(bC[p].x, bC[p].y, x, y, m1);   // ABA: outer flow B, gather A
        dir_meta(aC[p].x, aC[p].y, x, y, m2);   // BAB: outer flow A, gather B

        // tile eligibility: xb,xb+1 in cols, y0,y1 in rows (unsigned trick)
        bool e1 = ((unsigned)(m1.xb - tc0) <= (unsigned)(TILE_COLS - 2))
                & ((unsigned)(m1.y0 - tr0) < (unsigned)TILE_ROWS)
                & ((unsigned)(m1.y1 - tr0) < (unsigned)TILE_ROWS);
        bool e2 = ((unsigned)(m2.xb - tc0) <= (unsigned)(TILE_COLS - 2))
                & ((unsigned)(m2.y0 - tr0) < (unsigned)TILE_ROWS)
                & ((unsigned)(m2.y1 - tr0) < (unsigned)TILE_ROWS);

        float2a g1[4], g2[4];
        if (__all(e1 & e2)) {
            // 4 ds_read2_b64 total (2 per direction)
            int i10 = (m1.y0 - tr0) * LSTRIDE + (m1.xb - tc0);
            int i11 = (m1.y1 - tr0) * LSTRIDE + (m1.xb - tc0);
            ld_quad(ldsA, i10, g1[0], g1[1]);
            ld_quad(ldsA, i11, g1[2], g1[3]);
            int i20 = (m2.y0 - tr0) * LSTRIDE + (m2.xb - tc0);
            int i21 = (m2.y1 - tr0) * LSTRIDE + (m2.xb - tc0);
            ld_quad(ldsB, i20, g2[0], g2[1]);
            ld_quad(ldsB, i21, g2[2], g2[3]);
        } else {
            // rare: per-lane LDS/global select
            if (e1) {
                int i10 = (m1.y0 - tr0) * LSTRIDE + (m1.xb - tc0);
                int i11 = (m1.y1 - tr0) * LSTRIDE + (m1.xb - tc0);
                ld_quad(ldsA, i10, g1[0], g1[1]);
                ld_quad(ldsA, i11, g1[2], g1[3]);
            } else {
                int o0 = m1.y0 * W + m1.xb, o1 = m1.y1 * W + m1.xb;
                g1[0] = *(const float2a*)(Ab + o0);
                g1[1] = *(const float2a*)(Ab + HW + o0);
                g1[2] = *(const float2a*)(Ab + o1);
                g1[3] = *(const float2a*)(Ab + HW + o1);
            }
            if (e2) {
                int i20 = (m2.y0 - tr0) * LSTRIDE + (m2.xb - tc0);
                int i21 = (m2.y1 - tr0) * LSTRIDE + (m2.xb - tc0);
                ld_quad(ldsB, i20, g2[0], g2[1]);
                ld_quad(ldsB, i21, g2[2], g2[3]);
            } else {
                int o0 = m2.y0 * W + m2.xb, o1 = m2.y1 * W + m2.xb;
                g2[0] = *(const float2a*)(Bb + o0);
                g2[1] = *(const float2a*)(Bb + HW + o0);
                g2[2] = *(const float2a*)(Bb + o1);
                g2[3] = *(const float2a*)(Bb + HW + o1);
            }
        }

        bool ok = fast_ok(m1, g1[0], g1[1], g1[2], g1[3])
                & fast_ok(m2, g2[0], g2[1], g2[2], g2[3]);
        if (__all(ok)) {
            s += fast_eval(m1, g1[0], g1[1], g1[2], g1[3], bC[p].x, bC[p].y);
            s += fast_eval(m2, g2[0], g2[1], g2[2], g2[3], aC[p].x, aC[p].y);
        } else {
            s += dir_eval(m1, g1[0], g1[1], g1[2], g1[3], x, y);
            s += dir_eval(m2, g2[0], g2[1], g2[2], g2[3], x, y);
        }
    }

    // wave(64) shuffle reduce -> LDS -> one value per block
    #pragma unroll
    for (int o = 32; o > 0; o >>= 1) s += __shfl_down(s, o, 64);
    if (lane == 0) wsum[wv] = s;
    __syncthreads();
    if (tid == 0) {
        float tsum = wsum[0] + wsum[1] + wsum[2] + wsum[3];
        if (use_ws) {
            int bid = (blockIdx.z * gridDim.y + blockIdx.y) * gridDim.x + blockIdx.x;
            ws[bid] = tsum;                      // plain store, no atomics
        } else {
            atomicAdd(out, tsum * (1.0f / ((float)N * (float)H * (float)W)));
        }
    }
}

__global__ __launch_bounds__(256)
void reduce_kernel(const float* __restrict__ ws, float* __restrict__ out) {
    float s = 0.0f;
    for (int i = threadIdx.x; i < NBLOCKS; i += 256) s += ws[i];  // 36 iters
    #pragma unroll
    for (int o = 32; o > 0; o >>= 1) s += __shfl_down(s, o, 64);
    __shared__ float wsum[4];
    int lane = threadIdx.x & 63, wv = threadIdx.x >> 6;
    if (lane == 0) wsum[wv] = s;
    __syncthreads();
    if (threadIdx.x == 0) {
        float t = wsum[0] + wsum[1] + wsum[2] + wsum[3];
        out[0] = t * (1.0f / ((float)N * (float)H * (float)W));
    }
}

extern "C" void kernel_launch(void* const* d_in, const int* in_sizes, int n_in,
                              void* d_out, int out_size, void* d_ws, size_t ws_size,
                              hipStream_t stream) {
    const float* A = (const float*)d_in[0];   // UV_AtoB [16,2,768,768]
    const float* B = (const float*)d_in[1];   // UV_BtoA [16,2,768,768]
    float* out = (float*)d_out;               // scalar fp32
    float* ws  = (float*)d_ws;

    int use_ws = (ws_size >= NBLOCKS * sizeof(float)) ? 1 : 0;
    if (!use_ws) hipMemsetAsync(out, 0, sizeof(float), stream);

    dim3 grid(NBLK_X, NBLK_Y, N);             // (12, 48, 16) = 9216 blocks
    cycle_loss_kernel<<<grid, 256, 0, stream>>>(A, B, ws, out, use_ws);
    if (use_ws) reduce_kernel<<<1, 256, 0, stream>>>(ws, out);
}